// Round 1
// baseline (567.678 us; speedup 1.0000x reference)
//
#include <hip/hip_runtime.h>

#define CC   128      // channels
#define GG   4        // gates
#define BB   16       // batch
#define LL   32768    // length
#define TL   128      // l-positions per conv block
#define EPSV 1e-5f

// ---------------- Kernel 1: pool[b,c] = mean_l x[b,c,l] ----------------
__global__ __launch_bounds__(256) void pool_kernel(const float* __restrict__ x,
                                                   float* __restrict__ pool) {
    const int row = blockIdx.x;                  // b*CC + c, 0..2047
    const float4* xr = (const float4*)(x + (size_t)row * LL);
    const int t = threadIdx.x;
    float s = 0.f;
#pragma unroll
    for (int k = 0; k < (LL / 4) / 256; ++k) {   // 32 iterations
        float4 v = xr[t + k * 256];
        s += (v.x + v.y) + (v.z + v.w);
    }
    // wave reduce (64 lanes)
    for (int off = 32; off > 0; off >>= 1) s += __shfl_down(s, off, 64);
    __shared__ float red[4];
    if ((t & 63) == 0) red[t >> 6] = s;
    __syncthreads();
    if (t == 0) pool[row] = (red[0] + red[1] + red[2] + red[3]) * (1.0f / LL);
}

// ------- Kernel 2: gate (argmax of logits+gumbel) -> per-(b,c) affine -------
__global__ __launch_bounds__(256) void gate_kernel(const float* __restrict__ pool,
                                                   const float* __restrict__ gumbel,
                                                   const float* __restrict__ w_gate,
                                                   const float* __restrict__ conv_b,
                                                   const float* __restrict__ bn_w,
                                                   const float* __restrict__ bn_b,
                                                   const float* __restrict__ rmean,
                                                   const float* __restrict__ rvar,
                                                   float* __restrict__ Acoef,
                                                   float* __restrict__ Tcoef) {
    __shared__ float yl[BB][GG];
    __shared__ int   sidx[BB];
    const int t = threadIdx.x;
    if (t < BB * GG) {
        const int b = t / GG, g = t % GG;
        float s = 0.f;
        for (int c = 0; c < CC; ++c) s += pool[b * CC + c] * w_gate[g * CC + c];
        yl[b][g] = s + gumbel[b * GG + g];       // TAU = 1
    }
    __syncthreads();
    if (t < BB) {
        int best = 0; float bv = yl[t][0];
        for (int g = 1; g < GG; ++g) { if (yl[t][g] > bv) { bv = yl[t][g]; best = g; } }
        sidx[t] = best;                          // first-max tie-break, same as argmax
    }
    __syncthreads();
    for (int i = t; i < BB * CC; i += 256) {
        const int b = i / CC, c = i % CC;
        const int g = sidx[b];
        const int width = 32 * (g + 1);          // CHANNELS = {32,64,96,128}
        float a = 0.f, tt = 0.f;
        if (c < width) {
            const float inv = rsqrtf(rvar[g * CC + c] + EPSV);
            const float s = bn_w[c] * inv;
            a = s;
            tt = (conv_b[c] - rmean[g * CC + c]) * s + bn_b[c];
        }
        Acoef[i] = a;
        Tcoef[i] = tt;
    }
}

// ------- Kernel 3: out[b,o,l] = A[b,o] * (conv_w[o,:] . x[b,:,l]) + T[b,o] -------
// Block: 256 threads = 4 waves. Wave og owns outputs [og*32, og*32+32).
// Lane li owns l-pair (l0 + 2*li, l0 + 2*li + 1). TL=128 l per block.
__global__ __launch_bounds__(256, 2) void conv_kernel(const float* __restrict__ x,
                                                      const float* __restrict__ conv_w,
                                                      const float* __restrict__ Acoef,
                                                      const float* __restrict__ Tcoef,
                                                      float* __restrict__ out) {
    __shared__ float wlds[CC * CC];              // transposed: wlds[i*CC + o]
    __shared__ float sA[CC], sT[CC];
    const int b  = blockIdx.y;
    const int l0 = blockIdx.x * TL;
    const int t  = threadIdx.x;
    const int og = t >> 6;                       // 0..3 (wave id)
    const int li = t & 63;

    for (int idx = t; idx < CC * CC; idx += 256) {
        const int o = idx >> 7, i = idx & (CC - 1);
        wlds[i * CC + o] = conv_w[idx];          // one-time transposed stage
    }
    if (t < CC) { sA[t] = Acoef[b * CC + t]; sT[t] = Tcoef[b * CC + t]; }
    __syncthreads();

    float acc0[32], acc1[32];
#pragma unroll
    for (int j = 0; j < 32; ++j) { acc0[j] = 0.f; acc1[j] = 0.f; }

    const size_t xbase = (size_t)b * CC * LL + (size_t)l0 + 2 * li;
#pragma unroll 4
    for (int c = 0; c < CC; ++c) {
        const float2 xv = *(const float2*)(x + xbase + (size_t)c * LL);
        const float* wr = &wlds[c * CC + og * 32];   // wave-uniform, 128B aligned
#pragma unroll
        for (int j = 0; j < 32; ++j) {
            const float wv = wr[j];
            acc0[j] = fmaf(wv, xv.x, acc0[j]);
            acc1[j] = fmaf(wv, xv.y, acc1[j]);
        }
    }

    const size_t obase = (size_t)b * CC * LL + (size_t)l0 + 2 * li;
#pragma unroll
    for (int j = 0; j < 32; ++j) {
        const int o = og * 32 + j;
        const float s = sA[o], tt = sT[o];
        float2 r;
        r.x = fmaf(acc0[j], s, tt);
        r.y = fmaf(acc1[j], s, tt);
        *(float2*)(out + obase + (size_t)o * LL) = r;
    }
}

extern "C" void kernel_launch(void* const* d_in, const int* in_sizes, int n_in,
                              void* d_out, int out_size, void* d_ws, size_t ws_size,
                              hipStream_t stream) {
    const float* x      = (const float*)d_in[0];
    const float* gumbel = (const float*)d_in[1];
    const float* w_gate = (const float*)d_in[2];
    const float* conv_w = (const float*)d_in[3];
    const float* conv_b = (const float*)d_in[4];
    const float* bn_w   = (const float*)d_in[5];
    const float* bn_b   = (const float*)d_in[6];
    const float* rmean  = (const float*)d_in[7];
    const float* rvar   = (const float*)d_in[8];
    float* out = (float*)d_out;

    float* pool  = (float*)d_ws;                 // BB*CC floats
    float* Acoef = pool + BB * CC;               // BB*CC floats
    float* Tcoef = Acoef + BB * CC;              // BB*CC floats

    pool_kernel<<<BB * CC, 256, 0, stream>>>(x, pool);
    gate_kernel<<<1, 256, 0, stream>>>(pool, gumbel, w_gate, conv_b, bn_w, bn_b,
                                       rmean, rvar, Acoef, Tcoef);
    conv_kernel<<<dim3(LL / TL, BB), 256, 0, stream>>>(x, conv_w, Acoef, Tcoef, out);
}

// Round 2
// 174.395 us; speedup vs baseline: 3.2551x; 3.2551x over previous
//
#include <hip/hip_runtime.h>

#define CC   128      // channels
#define GG   4        // gates
#define BB   16       // batch
#define LL   32768    // length
#define TL   128      // l-positions per conv block
#define EPSV 1e-5f
#define WROW 136      // ushorts per LDS row = 272 B (256 B data + 16 B pad -> breaks bank aliasing)

typedef short short8 __attribute__((ext_vector_type(8)));
typedef float f32x16 __attribute__((ext_vector_type(16)));

__device__ inline unsigned short f2bf(float f) {   // RNE float->bf16
    union { float f; unsigned int u; } v; v.f = f;
    unsigned int r = (v.u + 0x7FFF + ((v.u >> 16) & 1)) >> 16;
    return (unsigned short)r;
}

// ---------------- Kernel 1: pool[b,c] = mean_l x[b,c,l] ----------------
__global__ __launch_bounds__(256) void pool_kernel(const float* __restrict__ x,
                                                   float* __restrict__ pool) {
    const int row = blockIdx.x;                  // b*CC + c
    const float4* xr = (const float4*)(x + (size_t)row * LL);
    const int t = threadIdx.x;
    float s = 0.f;
#pragma unroll
    for (int k = 0; k < (LL / 4) / 256; ++k) {
        float4 v = xr[t + k * 256];
        s += (v.x + v.y) + (v.z + v.w);
    }
    for (int off = 32; off > 0; off >>= 1) s += __shfl_down(s, off, 64);
    __shared__ float red[4];
    if ((t & 63) == 0) red[t >> 6] = s;
    __syncthreads();
    if (t == 0) pool[row] = (red[0] + red[1] + red[2] + red[3]) * (1.0f / LL);
}

// ------- Kernel 2: gate (argmax of logits+gumbel) -> per-(b,c) affine -------
__global__ __launch_bounds__(256) void gate_kernel(const float* __restrict__ pool,
                                                   const float* __restrict__ gumbel,
                                                   const float* __restrict__ w_gate,
                                                   const float* __restrict__ conv_b,
                                                   const float* __restrict__ bn_w,
                                                   const float* __restrict__ bn_b,
                                                   const float* __restrict__ rmean,
                                                   const float* __restrict__ rvar,
                                                   float* __restrict__ Acoef,
                                                   float* __restrict__ Tcoef) {
    __shared__ float yl[BB][GG];
    __shared__ int   sidx[BB];
    const int t = threadIdx.x;
    if (t < BB * GG) {
        const int b = t / GG, g = t % GG;
        float s = 0.f;
        for (int c = 0; c < CC; ++c) s += pool[b * CC + c] * w_gate[g * CC + c];
        yl[b][g] = s + gumbel[b * GG + g];
    }
    __syncthreads();
    if (t < BB) {
        int best = 0; float bv = yl[t][0];
        for (int g = 1; g < GG; ++g) { if (yl[t][g] > bv) { bv = yl[t][g]; best = g; } }
        sidx[t] = best;
    }
    __syncthreads();
    for (int i = t; i < BB * CC; i += 256) {
        const int b = i / CC, c = i % CC;
        const int g = sidx[b];
        const int width = 32 * (g + 1);
        float a = 0.f, tt = 0.f;
        if (c < width) {
            const float inv = rsqrtf(rvar[g * CC + c] + EPSV);
            const float s = bn_w[c] * inv;
            a = s;
            tt = (conv_b[c] - rmean[g * CC + c]) * s + bn_b[c];
        }
        Acoef[i] = a;
        Tcoef[i] = tt;
    }
}

// ------- Kernel 3 (MFMA): out[b,o,l] = A[b,o]*(W @ x[b,:,l])[o] + T[b,o] -------
// Block = 256 threads = 4 waves; wave og owns o-range [og*32, og*32+32).
// Block tile: M=128 (all o) x N=128 l, K=128. mfma_f32_32x32x16_bf16, 8 k-steps.
// LDS: W bf16 [o][i] rows of 272B; xT bf16 [l][i] rows of 272B (transposed during staging).
__global__ __launch_bounds__(256, 2) void conv_kernel(const float* __restrict__ x,
                                                      const float* __restrict__ conv_w,
                                                      const float* __restrict__ Acoef,
                                                      const float* __restrict__ Tcoef,
                                                      float* __restrict__ out) {
    extern __shared__ char smem[];
    unsigned short* wlds = (unsigned short*)smem;            // CC * WROW
    unsigned short* xlds = wlds + CC * WROW;                 // TL * WROW
    float* sA = (float*)(xlds + TL * WROW);                  // CC
    float* sT = sA + CC;                                     // CC

    const int b  = blockIdx.y;
    const int l0 = blockIdx.x * TL;
    const int t  = threadIdx.x;
    const int lane = t & 63;
    const int og   = t >> 6;
    const int m  = lane & 31;
    const int kh = lane >> 5;     // 0/1: which k-half of the fragment

    // ---- stage W: [o][i] fp32 -> bf16, row stride WROW ----
#pragma unroll
    for (int it = 0; it < 16; ++it) {
        const int idx = it * 256 + t;            // 0..4095
        const int o  = idx >> 5;                 // 32 float4 per 128-wide row
        const int iq = (idx & 31) * 4;
        const float4 wv = *(const float4*)(conv_w + o * CC + iq);
        ushort4 u;
        u.x = f2bf(wv.x); u.y = f2bf(wv.y); u.z = f2bf(wv.z); u.w = f2bf(wv.w);
        *(ushort4*)&wlds[o * WROW + iq] = u;     // 8B write, 8B-aligned (272B rows)
    }
    // ---- stage x transposed: xT[l][i], 4 strided dword loads (each coalesced) ----
    const float* xb = x + (size_t)b * CC * LL + l0;
#pragma unroll
    for (int it = 0; it < 16; ++it) {
        const int idx = it * 256 + t;            // 0..4095
        const int l  = idx & 127;
        const int i0 = (idx >> 7) * 4;
        const float v0 = xb[(size_t)(i0 + 0) * LL + l];
        const float v1 = xb[(size_t)(i0 + 1) * LL + l];
        const float v2 = xb[(size_t)(i0 + 2) * LL + l];
        const float v3 = xb[(size_t)(i0 + 3) * LL + l];
        ushort4 u;
        u.x = f2bf(v0); u.y = f2bf(v1); u.z = f2bf(v2); u.w = f2bf(v3);
        *(ushort4*)&xlds[l * WROW + i0] = u;
    }
    if (t < CC) { sA[t] = Acoef[b * CC + t]; sT[t] = Tcoef[b * CC + t]; }
    __syncthreads();

    // ---- MFMA K-loop: 8 k-steps of 16, 4 n-tiles of 32 ----
    f32x16 acc[4];
#pragma unroll
    for (int nt = 0; nt < 4; ++nt)
#pragma unroll
        for (int r = 0; r < 16; ++r) acc[nt][r] = 0.f;

#pragma unroll
    for (int ks = 0; ks < 8; ++ks) {
        const short8 a = *(const short8*)&wlds[(og * 32 + m) * WROW + ks * 16 + kh * 8];
#pragma unroll
        for (int nt = 0; nt < 4; ++nt) {
            const short8 bf = *(const short8*)&xlds[(nt * 32 + m) * WROW + ks * 16 + kh * 8];
            acc[nt] = __builtin_amdgcn_mfma_f32_32x32x16_bf16(a, bf, acc[nt], 0, 0, 0);
        }
    }

    // ---- epilogue: per-(b,o) affine, coalesced stores (2x128B per instr) ----
    float sreg[16], treg[16];
#pragma unroll
    for (int r = 0; r < 16; ++r) {
        const int o = og * 32 + (r & 3) + 8 * (r >> 2) + 4 * kh;
        sreg[r] = sA[o]; treg[r] = sT[o];
    }
    float* ob = out + (size_t)b * CC * LL + l0;
#pragma unroll
    for (int nt = 0; nt < 4; ++nt) {
#pragma unroll
        for (int r = 0; r < 16; ++r) {
            const int o = og * 32 + (r & 3) + 8 * (r >> 2) + 4 * kh;
            ob[(size_t)o * LL + nt * 32 + m] = fmaf(acc[nt][r], sreg[r], treg[r]);
        }
    }
}

extern "C" void kernel_launch(void* const* d_in, const int* in_sizes, int n_in,
                              void* d_out, int out_size, void* d_ws, size_t ws_size,
                              hipStream_t stream) {
    const float* x      = (const float*)d_in[0];
    const float* gumbel = (const float*)d_in[1];
    const float* w_gate = (const float*)d_in[2];
    const float* conv_w = (const float*)d_in[3];
    const float* conv_b = (const float*)d_in[4];
    const float* bn_w   = (const float*)d_in[5];
    const float* bn_b   = (const float*)d_in[6];
    const float* rmean  = (const float*)d_in[7];
    const float* rvar   = (const float*)d_in[8];
    float* out = (float*)d_out;

    float* pool  = (float*)d_ws;
    float* Acoef = pool + BB * CC;
    float* Tcoef = Acoef + BB * CC;

    pool_kernel<<<BB * CC, 256, 0, stream>>>(x, pool);
    gate_kernel<<<1, 256, 0, stream>>>(pool, gumbel, w_gate, conv_b, bn_w, bn_b,
                                       rmean, rvar, Acoef, Tcoef);

    const size_t smem = (size_t)(CC + TL) * WROW * sizeof(unsigned short)
                      + 2 * CC * sizeof(float);              // 70656 B -> 2 blocks/CU
    conv_kernel<<<dim3(LL / TL, BB), 256, smem, stream>>>(x, conv_w, Acoef, Tcoef, out);
}

// Round 3
// 130.694 us; speedup vs baseline: 4.3436x; 1.3344x over previous
//
#include <hip/hip_runtime.h>

#define CC   128      // channels
#define GG   4        // gates
#define BB   16       // batch
#define LL   32768    // length
#define TL   128      // l-positions per conv block
#define EPSV 1e-5f
#define WROW 136      // ushorts per LDS row = 272 B (breaks power-of-2 bank aliasing)

typedef short short8 __attribute__((ext_vector_type(8)));
typedef float f32x16 __attribute__((ext_vector_type(16)));

__device__ inline unsigned short f2bf(float f) {   // RNE float->bf16
    union { float f; unsigned int u; } v; v.f = f;
    unsigned int r = (v.u + 0x7FFF + ((v.u >> 16) & 1)) >> 16;
    return (unsigned short)r;
}

// ---------------- Kernel 1: pool[b,c] = mean_l x[b,c,l] ----------------
__global__ __launch_bounds__(256) void pool_kernel(const float* __restrict__ x,
                                                   float* __restrict__ pool) {
    const int row = blockIdx.x;                  // b*CC + c
    const float4* xr = (const float4*)(x + (size_t)row * LL);
    const int t = threadIdx.x;
    float s = 0.f;
#pragma unroll
    for (int k = 0; k < (LL / 4) / 256; ++k) {
        float4 v = xr[t + k * 256];
        s += (v.x + v.y) + (v.z + v.w);
    }
    for (int off = 32; off > 0; off >>= 1) s += __shfl_down(s, off, 64);
    __shared__ float red[4];
    if ((t & 63) == 0) red[t >> 6] = s;
    __syncthreads();
    if (t == 0) pool[row] = (red[0] + red[1] + red[2] + red[3]) * (1.0f / LL);
}

// ------- Kernel 2: gate (argmax of logits+gumbel) -> per-(b,c) affine -------
__global__ __launch_bounds__(256) void gate_kernel(const float* __restrict__ pool,
                                                   const float* __restrict__ gumbel,
                                                   const float* __restrict__ w_gate,
                                                   const float* __restrict__ conv_b,
                                                   const float* __restrict__ bn_w,
                                                   const float* __restrict__ bn_b,
                                                   const float* __restrict__ rmean,
                                                   const float* __restrict__ rvar,
                                                   float* __restrict__ Acoef,
                                                   float* __restrict__ Tcoef) {
    __shared__ float yl[BB][GG];
    __shared__ int   sidx[BB];
    const int t = threadIdx.x;
    if (t < BB * GG) {
        const int b = t / GG, g = t % GG;
        float s = 0.f;
        for (int c = 0; c < CC; ++c) s += pool[b * CC + c] * w_gate[g * CC + c];
        yl[b][g] = s + gumbel[b * GG + g];
    }
    __syncthreads();
    if (t < BB) {
        int best = 0; float bv = yl[t][0];
        for (int g = 1; g < GG; ++g) { if (yl[t][g] > bv) { bv = yl[t][g]; best = g; } }
        sidx[t] = best;
    }
    __syncthreads();
    for (int i = t; i < BB * CC; i += 256) {
        const int b = i / CC, c = i % CC;
        const int g = sidx[b];
        const int width = 32 * (g + 1);
        float a = 0.f, tt = 0.f;
        if (c < width) {
            const float inv = rsqrtf(rvar[g * CC + c] + EPSV);
            const float s = bn_w[c] * inv;
            a = s;
            tt = (conv_b[c] - rmean[g * CC + c]) * s + bn_b[c];
        }
        Acoef[i] = a;
        Tcoef[i] = tt;
    }
}

// ------- Kernel 3 (MFMA): out[b,o,l] = A[b,o]*(W @ x[b,:,l])[o] + T[b,o] -------
// Block = 256 threads = 4 waves; wave og owns o-range [og*32, og*32+32).
// W A-fragments live in registers (32 VGPR/thread), loaded from global (L2-hot).
// LDS holds only the transposed x tile -> 35.8 KiB -> 4 blocks/CU.
// Conv x reads + out stores are non-temporal so L3 retains x for this 2nd pass.
__global__ __launch_bounds__(256, 4) void conv_kernel(const float* __restrict__ x,
                                                      const float* __restrict__ conv_w,
                                                      const float* __restrict__ Acoef,
                                                      const float* __restrict__ Tcoef,
                                                      float* __restrict__ out) {
    __shared__ unsigned short xlds[TL * WROW];   // 34,816 B
    __shared__ float sA[CC], sT[CC];

    const int b  = blockIdx.y;
    const int l0 = blockIdx.x * TL;
    const int t  = threadIdx.x;
    const int lane = t & 63;
    const int og   = t >> 6;
    const int m  = lane & 31;
    const int kh = lane >> 5;     // 0/1: which k-half of the fragment

    if (t < CC) { sA[t] = Acoef[b * CC + t]; sT[t] = Tcoef[b * CC + t]; }

    // ---- W A-fragments -> registers: lane (m,kh) holds W[og*32+m][ks*16+kh*8 .. +7] ----
    short8 wfrag[8];
    {
        const float* wr = conv_w + (og * 32 + m) * CC + kh * 8;
#pragma unroll
        for (int ks = 0; ks < 8; ++ks) {
            const float4 a = *(const float4*)(wr + ks * 16);
            const float4 c = *(const float4*)(wr + ks * 16 + 4);
            short8 f;
            f[0] = (short)f2bf(a.x); f[1] = (short)f2bf(a.y);
            f[2] = (short)f2bf(a.z); f[3] = (short)f2bf(a.w);
            f[4] = (short)f2bf(c.x); f[5] = (short)f2bf(c.y);
            f[6] = (short)f2bf(c.z); f[7] = (short)f2bf(c.w);
            wfrag[ks] = f;
        }
    }

    // ---- stage x transposed: xT[l][i] bf16, rows of 272 B ----
    const float* xb = x + (size_t)b * CC * LL + l0;
#pragma unroll
    for (int it = 0; it < 16; ++it) {
        const int idx = it * 256 + t;            // 0..4095
        const int l  = idx & 127;
        const int i0 = (idx >> 7) * 4;
        const float v0 = __builtin_nontemporal_load(xb + (size_t)(i0 + 0) * LL + l);
        const float v1 = __builtin_nontemporal_load(xb + (size_t)(i0 + 1) * LL + l);
        const float v2 = __builtin_nontemporal_load(xb + (size_t)(i0 + 2) * LL + l);
        const float v3 = __builtin_nontemporal_load(xb + (size_t)(i0 + 3) * LL + l);
        ushort4 u;
        u.x = f2bf(v0); u.y = f2bf(v1); u.z = f2bf(v2); u.w = f2bf(v3);
        *(ushort4*)&xlds[l * WROW + i0] = u;
    }
    __syncthreads();

    // ---- MFMA K-loop: 8 k-steps of 16, 4 n-tiles of 32 ----
    f32x16 acc[4];
#pragma unroll
    for (int nt = 0; nt < 4; ++nt)
#pragma unroll
        for (int r = 0; r < 16; ++r) acc[nt][r] = 0.f;

#pragma unroll
    for (int ks = 0; ks < 8; ++ks) {
#pragma unroll
        for (int nt = 0; nt < 4; ++nt) {
            const short8 bf = *(const short8*)&xlds[(nt * 32 + m) * WROW + ks * 16 + kh * 8];
            acc[nt] = __builtin_amdgcn_mfma_f32_32x32x16_bf16(wfrag[ks], bf, acc[nt], 0, 0, 0);
        }
    }

    // ---- epilogue: per-(b,o) affine, non-temporal coalesced stores ----
    float sreg[16], treg[16];
#pragma unroll
    for (int r = 0; r < 16; ++r) {
        const int o = og * 32 + (r & 3) + 8 * (r >> 2) + 4 * kh;
        sreg[r] = sA[o]; treg[r] = sT[o];
    }
    float* ob = out + (size_t)b * CC * LL + l0;
#pragma unroll
    for (int nt = 0; nt < 4; ++nt) {
#pragma unroll
        for (int r = 0; r < 16; ++r) {
            const int o = og * 32 + (r & 3) + 8 * (r >> 2) + 4 * kh;
            __builtin_nontemporal_store(fmaf(acc[nt][r], sreg[r], treg[r]),
                                        ob + (size_t)o * LL + nt * 32 + m);
        }
    }
}

extern "C" void kernel_launch(void* const* d_in, const int* in_sizes, int n_in,
                              void* d_out, int out_size, void* d_ws, size_t ws_size,
                              hipStream_t stream) {
    const float* x      = (const float*)d_in[0];
    const float* gumbel = (const float*)d_in[1];
    const float* w_gate = (const float*)d_in[2];
    const float* conv_w = (const float*)d_in[3];
    const float* conv_b = (const float*)d_in[4];
    const float* bn_w   = (const float*)d_in[5];
    const float* bn_b   = (const float*)d_in[6];
    const float* rmean  = (const float*)d_in[7];
    const float* rvar   = (const float*)d_in[8];
    float* out = (float*)d_out;

    float* pool  = (float*)d_ws;
    float* Acoef = pool + BB * CC;
    float* Tcoef = Acoef + BB * CC;

    pool_kernel<<<BB * CC, 256, 0, stream>>>(x, pool);
    gate_kernel<<<1, 256, 0, stream>>>(pool, gumbel, w_gate, conv_b, bn_w, bn_b,
                                       rmean, rvar, Acoef, Tcoef);
    conv_kernel<<<dim3(LL / TL, BB), 256, 0, stream>>>(x, conv_w, Acoef, Tcoef, out);
}

// Round 4
// 128.684 us; speedup vs baseline: 4.4114x; 1.0156x over previous
//
#include <hip/hip_runtime.h>

#define CC   128      // channels
#define GG   4        // gates
#define BB   16       // batch
#define LL   32768    // length
#define TL   128      // l-positions per conv block
#define EPSV 1e-5f
#define WROW 136      // ushorts per LDS row = 272 B (breaks power-of-2 bank aliasing)

typedef short short8 __attribute__((ext_vector_type(8)));
typedef float f32x16 __attribute__((ext_vector_type(16)));

__device__ inline unsigned short f2bf(float f) {   // RNE float->bf16
    union { float f; unsigned int u; } v; v.f = f;
    unsigned int r = (v.u + 0x7FFF + ((v.u >> 16) & 1)) >> 16;
    return (unsigned short)r;
}

// ---------------- Kernel 1: pool[b,c] = mean_l x[b,c,l] ----------------
// Temporal loads on purpose: establishes x in L3 for the conv pass (and for
// subsequent graph replays).
__global__ __launch_bounds__(256) void pool_kernel(const float* __restrict__ x,
                                                   float* __restrict__ pool) {
    const int row = blockIdx.x;                  // b*CC + c
    const float4* xr = (const float4*)(x + (size_t)row * LL);
    const int t = threadIdx.x;
    float s = 0.f;
#pragma unroll
    for (int k = 0; k < (LL / 4) / 256; ++k) {
        float4 v = xr[t + k * 256];
        s += (v.x + v.y) + (v.z + v.w);
    }
    for (int off = 32; off > 0; off >>= 1) s += __shfl_down(s, off, 64);
    __shared__ float red[4];
    if ((t & 63) == 0) red[t >> 6] = s;
    __syncthreads();
    if (t == 0) pool[row] = (red[0] + red[1] + red[2] + red[3]) * (1.0f / LL);
}

// ------- Kernel 2: gate (argmax of logits+gumbel) -> per-(b,c) affine -------
__global__ __launch_bounds__(256) void gate_kernel(const float* __restrict__ pool,
                                                   const float* __restrict__ gumbel,
                                                   const float* __restrict__ w_gate,
                                                   const float* __restrict__ conv_b,
                                                   const float* __restrict__ bn_w,
                                                   const float* __restrict__ bn_b,
                                                   const float* __restrict__ rmean,
                                                   const float* __restrict__ rvar,
                                                   float* __restrict__ Acoef,
                                                   float* __restrict__ Tcoef) {
    __shared__ float yl[BB][GG];
    __shared__ int   sidx[BB];
    const int t = threadIdx.x;
    if (t < BB * GG) {
        const int b = t / GG, g = t % GG;
        float s = 0.f;
        for (int c = 0; c < CC; ++c) s += pool[b * CC + c] * w_gate[g * CC + c];
        yl[b][g] = s + gumbel[b * GG + g];
    }
    __syncthreads();
    if (t < BB) {
        int best = 0; float bv = yl[t][0];
        for (int g = 1; g < GG; ++g) { if (yl[t][g] > bv) { bv = yl[t][g]; best = g; } }
        sidx[t] = best;
    }
    __syncthreads();
    for (int i = t; i < BB * CC; i += 256) {
        const int b = i / CC, c = i % CC;
        const int g = sidx[b];
        const int width = 32 * (g + 1);
        float a = 0.f, tt = 0.f;
        if (c < width) {
            const float inv = rsqrtf(rvar[g * CC + c] + EPSV);
            const float s = bn_w[c] * inv;
            a = s;
            tt = (conv_b[c] - rmean[g * CC + c]) * s + bn_b[c];
        }
        Acoef[i] = a;
        Tcoef[i] = tt;
    }
}

// ------- Kernel 3 (MFMA): out[b,o,l] = A[b,o]*(W @ x[b,:,l])[o] + T[b,o] -------
// Block = 256 threads = 4 waves; wave og owns o-range [og*32, og*32+32).
// W A-fragments in registers; LDS holds only transposed x tile (4 blocks/CU).
// x reads are TEMPORAL (want L3 hits / retention); out stores non-temporal
// (dead data -> don't evict x from L3).
__global__ __launch_bounds__(256, 4) void conv_kernel(const float* __restrict__ x,
                                                      const float* __restrict__ conv_w,
                                                      const float* __restrict__ Acoef,
                                                      const float* __restrict__ Tcoef,
                                                      float* __restrict__ out) {
    __shared__ unsigned short xlds[TL * WROW];   // 34,816 B
    __shared__ float sA[CC], sT[CC];

    const int b  = blockIdx.y;
    const int l0 = blockIdx.x * TL;
    const int t  = threadIdx.x;
    const int lane = t & 63;
    const int og   = t >> 6;
    const int m  = lane & 31;
    const int kh = lane >> 5;     // 0/1: which k-half of the fragment

    if (t < CC) { sA[t] = Acoef[b * CC + t]; sT[t] = Tcoef[b * CC + t]; }

    // ---- W A-fragments -> registers: lane (m,kh) holds W[og*32+m][ks*16+kh*8 .. +7] ----
    short8 wfrag[8];
    {
        const float* wr = conv_w + (og * 32 + m) * CC + kh * 8;
#pragma unroll
        for (int ks = 0; ks < 8; ++ks) {
            const float4 a = *(const float4*)(wr + ks * 16);
            const float4 c = *(const float4*)(wr + ks * 16 + 4);
            short8 f;
            f[0] = (short)f2bf(a.x); f[1] = (short)f2bf(a.y);
            f[2] = (short)f2bf(a.z); f[3] = (short)f2bf(a.w);
            f[4] = (short)f2bf(c.x); f[5] = (short)f2bf(c.y);
            f[6] = (short)f2bf(c.z); f[7] = (short)f2bf(c.w);
            wfrag[ks] = f;
        }
    }

    // ---- stage x transposed: xT[l][i] bf16, rows of 272 B (temporal loads) ----
    const float* xb = x + (size_t)b * CC * LL + l0;
#pragma unroll
    for (int it = 0; it < 16; ++it) {
        const int idx = it * 256 + t;            // 0..4095
        const int l  = idx & 127;
        const int i0 = (idx >> 7) * 4;
        const float v0 = xb[(size_t)(i0 + 0) * LL + l];
        const float v1 = xb[(size_t)(i0 + 1) * LL + l];
        const float v2 = xb[(size_t)(i0 + 2) * LL + l];
        const float v3 = xb[(size_t)(i0 + 3) * LL + l];
        ushort4 u;
        u.x = f2bf(v0); u.y = f2bf(v1); u.z = f2bf(v2); u.w = f2bf(v3);
        *(ushort4*)&xlds[l * WROW + i0] = u;
    }
    __syncthreads();

    // ---- MFMA K-loop: 8 k-steps of 16, 4 n-tiles of 32 ----
    f32x16 acc[4];
#pragma unroll
    for (int nt = 0; nt < 4; ++nt)
#pragma unroll
        for (int r = 0; r < 16; ++r) acc[nt][r] = 0.f;

#pragma unroll
    for (int ks = 0; ks < 8; ++ks) {
#pragma unroll
        for (int nt = 0; nt < 4; ++nt) {
            const short8 bf = *(const short8*)&xlds[(nt * 32 + m) * WROW + ks * 16 + kh * 8];
            acc[nt] = __builtin_amdgcn_mfma_f32_32x32x16_bf16(wfrag[ks], bf, acc[nt], 0, 0, 0);
        }
    }

    // ---- epilogue: per-(b,o) affine, non-temporal coalesced stores ----
    float sreg[16], treg[16];
#pragma unroll
    for (int r = 0; r < 16; ++r) {
        const int o = og * 32 + (r & 3) + 8 * (r >> 2) + 4 * kh;
        sreg[r] = sA[o]; treg[r] = sT[o];
    }
    float* ob = out + (size_t)b * CC * LL + l0;
#pragma unroll
    for (int nt = 0; nt < 4; ++nt) {
#pragma unroll
        for (int r = 0; r < 16; ++r) {
            const int o = og * 32 + (r & 3) + 8 * (r >> 2) + 4 * kh;
            __builtin_nontemporal_store(fmaf(acc[nt][r], sreg[r], treg[r]),
                                        ob + (size_t)o * LL + nt * 32 + m);
        }
    }
}

extern "C" void kernel_launch(void* const* d_in, const int* in_sizes, int n_in,
                              void* d_out, int out_size, void* d_ws, size_t ws_size,
                              hipStream_t stream) {
    const float* x      = (const float*)d_in[0];
    const float* gumbel = (const float*)d_in[1];
    const float* w_gate = (const float*)d_in[2];
    const float* conv_w = (const float*)d_in[3];
    const float* conv_b = (const float*)d_in[4];
    const float* bn_w   = (const float*)d_in[5];
    const float* bn_b   = (const float*)d_in[6];
    const float* rmean  = (const float*)d_in[7];
    const float* rvar   = (const float*)d_in[8];
    float* out = (float*)d_out;

    float* pool  = (float*)d_ws;
    float* Acoef = pool + BB * CC;
    float* Tcoef = Acoef + BB * CC;

    pool_kernel<<<BB * CC, 256, 0, stream>>>(x, pool);
    gate_kernel<<<1, 256, 0, stream>>>(pool, gumbel, w_gate, conv_b, bn_w, bn_b,
                                       rmean, rvar, Acoef, Tcoef);
    conv_kernel<<<dim3(LL / TL, BB), 256, 0, stream>>>(x, conv_w, Acoef, Tcoef, out);
}